// Round 10
// baseline (282.161 us; speedup 1.0000x reference)
//
#include <hip/hip_runtime.h>
#include <hip/hip_fp16.h>

// ---------------------------------------------------------------------------
// RelGraphConv (basis-decomposed, right-norm, sum over relations) on MI355X.
//
//   h[d] = B0^T * A0[d] + B1^T * A1[d] + x[d]@Wl + bias,  ReLU
//   A_b[d] = sum_{edges e->d} (coeff[r_e][b]/deg[r_e][d]) * x[src_e]
// R16: quarter-wave 16-edge predicated gather: 100us.
// R17/R18/R20: edge-centric stream / dual-node / lookback+cursor all
//   REGRESSED -> reverted.
// R19: LDS-staged recs + quarter-wave-owns-node gather.
// R21/R22: coop-fused pre: correct at 512 blocks but starved (23.7% occ);
//   2048-block coop launch poisons graph capture. Abandoned. Counters
//   exposed recs scatter write-amplification (WRITE 111MB vs ~45 logical).
// R23 (banked best, 281.5us): R19 pipeline minus scan_mid (scan_write
//   self-computes chunk base from raw bsums). NOTE: gather_gemm 97->108us
//   on identical code = cross-session clock variance; trust within-session.
// R24: 4-BYTE EDGE RECORDS. rec = src | r<<17 (src<2^17, r<8). Per-block
//   LDS table ccL[32][8] = coeff[r][b]/deg[r][d] (256 thr, one coalesced
//   deg read each, once per block) replaces per-edge half2 coeffs.
//   recs 9.6->4.8MB; fill scatter lines 2x denser (the 111MB excess);
//   recsL LDS 8->4KB -> 23.2KB/block -> 7 blocks/CU by LDS (occ 45->~60);
//   coeffs in f32 (numerics improve). cnt array eliminated (scan_write
//   sums its own deg reads). fill no longer reads coeff.
// ---------------------------------------------------------------------------

#define DFEAT 128
#define NREL 8
#define ALDA 264   // LDS agg row stride in ushorts (256 data + 8 pad)
#define ECAP 1024  // staged-recs capacity (block edge count ~Poisson(384))

typedef __attribute__((ext_vector_type(8))) short bf16x8;
typedef __attribute__((ext_vector_type(4))) float f32x4;
typedef __attribute__((ext_vector_type(2))) float f32x2;

__device__ __forceinline__ ushort f2bf(float f) {
    unsigned u = __float_as_uint(f);
    u += 0x7FFF + ((u >> 16) & 1);          // round-to-nearest-even
    return (ushort)(u >> 16);
}
__device__ __forceinline__ float bflo(unsigned u) { return __uint_as_float(u << 16); }
__device__ __forceinline__ float bfhi(unsigned u) { return __uint_as_float(u & 0xFFFF0000u); }
__device__ __forceinline__ unsigned pack2bf(float lo, float hi) {
    return (unsigned)f2bf(lo) | ((unsigned)f2bf(hi) << 16);
}

// Fused: count_rank (atomic-latency-bound) + convert_x + build_w2T (BW-bound).
// deg must be pre-zeroed. w2T[j][k]: k<256 -> bases[k>>7][k&127][j],
// else loopw[k-256][j].
__global__ void fused_pre(const int* __restrict__ dst, int* __restrict__ deg,
                          ushort* __restrict__ rank,
                          const float* __restrict__ x, ushort* __restrict__ xb,
                          const float* __restrict__ bases, const float* __restrict__ loopw,
                          ushort* __restrict__ w2T,
                          int RE, int E, int N, int n4) {
    const int stride = gridDim.x * blockDim.x;
    const int t0 = blockIdx.x * blockDim.x + threadIdx.x;
    for (int i = t0; i < RE; i += stride) {
        int r = i / E;
        int d = dst[i];
        rank[i] = (ushort)atomicAdd(&deg[r * N + d], 1);
    }
    for (int i = t0; i < n4; i += stride) {
        float4 v = ((const float4*)x)[i];
        ushort4 o;
        o.x = f2bf(v.x); o.y = f2bf(v.y); o.z = f2bf(v.z); o.w = f2bf(v.w);
        ((ushort4*)xb)[i] = o;
    }
    for (int i = t0; i < 128 * 384; i += stride) {
        int j = i / 384, k = i % 384;
        float v = (k < 256) ? bases[(k >> 7) * DFEAT * DFEAT + (k & 127) * DFEAT + j]
                            : loopw[(k - 256) * DFEAT + j];
        w2T[i] = f2bf(v);
    }
}

// Per 256-node chunk: bsums[b] = sum over chunk of (sum_r deg[r][d]).
__global__ void scan_block_sums(const int* __restrict__ deg,
                                int* __restrict__ bsums, int N) {
    __shared__ int sdata[256];
    int b = blockIdx.x, t = threadIdx.x;
    int idx = b * 256 + t;
    int sum = 0;
    if (idx < N) {
        #pragma unroll
        for (int r = 0; r < NREL; ++r) sum += deg[r * N + idx];
    }
    sdata[t] = sum; __syncthreads();
    for (int s = 128; s > 0; s >>= 1) {
        if (t < s) sdata[t] += sdata[t + s];
        __syncthreads();
    }
    if (t == 0) bsums[b] = sdata[0];
}

// rowStart[d] + packed[r*N+d] = ((rowStart[d]+prefix_r)<<11)|deg_rd.
// Self-computes chunk base = sum bsums[0..b) (raw, L2-hot, <=391 ints).
// R24: per-node cnt computed inline from the deg reads it needs anyway.
__global__ void scan_write(const int* __restrict__ bsums,
                           const int* __restrict__ deg,
                           int* __restrict__ rowStart, unsigned* __restrict__ packed,
                           int N) {
    __shared__ int sdata[256];
    int b = blockIdx.x, t = threadIdx.x;

    // chunk base: sum of raw bsums[0..b)
    int part = 0;
    for (int k = t; k < b; k += 256) part += bsums[k];
    sdata[t] = part; __syncthreads();
    for (int s = 128; s > 0; s >>= 1) {
        if (t < s) sdata[t] += sdata[t + s];
        __syncthreads();
    }
    const int boff = sdata[0];
    __syncthreads();

    // per-node degree sum (kept in regs for packed below)
    int idx = b * 256 + t;
    int dvs[NREL];
    int c = 0;
    if (idx < N) {
        #pragma unroll
        for (int r = 0; r < NREL; ++r) { dvs[r] = deg[r * N + idx]; c += dvs[r]; }
    }
    // local exclusive scan
    sdata[t] = c; __syncthreads();
    for (int off = 1; off < 256; off <<= 1) {
        int x = 0;
        if (t >= off) x = sdata[t - off];
        __syncthreads();
        if (t >= off) sdata[t] += x;
        __syncthreads();
    }
    int excl = sdata[t] - c;
    if (idx < N) {
        int rs = boff + excl;
        rowStart[idx] = rs;
        int pre = 0;
        #pragma unroll
        for (int r = 0; r < NREL; ++r) {
            int dv = dvs[r];
            packed[r * N + idx] = ((unsigned)(rs + pre) << 11) | (unsigned)dv;
            pre += dv;
        }
    }
}

// Atomic-free placement: pos = (packed>>11) + rank. ONE random read per edge.
// R24: 4-byte record = src | r<<17. No coeff/deg payload.
__global__ void fill_kernel(const int* __restrict__ src, const int* __restrict__ dst,
                            const ushort* __restrict__ rank,
                            const unsigned* __restrict__ packed,
                            unsigned* __restrict__ recs, int RE, int E, int N) {
    int idx = blockIdx.x * blockDim.x + threadIdx.x;
    if (idx >= RE) return;
    int r = idx / E;
    int d = dst[idx];
    unsigned p = packed[r * N + d];
    int pos = (int)(p >> 11) + (int)rank[idx];
    recs[pos] = (unsigned)src[idx] | ((unsigned)r << 17);
}

// ---------------------------------------------------------------------------
// FUSED gather + GEMM. Block = 32 dst nodes. LDS: agg 16.9KB + recsL 4KB +
// ccL 2KB + rsl = 23.2KB -> up to 7 blocks/CU by LDS.
// Phase 0: stage rowStart[row0..row0+32], ccL[i][r]=coeff[r][b]/deg[r][d]
//   (256 thr, coalesced deg reads), and recs[e0..e1) into LDS.
// Phase 1: quarter-wave owns a node; 8-edge rounds, rec+cc from LDS
//   (broadcast), xb uint4 gather. f32 accumulate -> bf16 agg.
// Phase 2: out[32,128] = relu([aggLDS|xb][32,384] @ w2T^T + bias).
// ---------------------------------------------------------------------------
__global__ __launch_bounds__(256, 6) void gather_gemm(
    const unsigned* __restrict__ recs, const int* __restrict__ rowStart,
    const int* __restrict__ deg, const float* __restrict__ coeff,
    const ushort* __restrict__ xb,
    const ushort* __restrict__ w2T, const float* __restrict__ bias,
    float* __restrict__ out, int N, int RE) {
    __shared__ __align__(16) ushort agg[32 * ALDA];   // 16.9 KB
    __shared__ __align__(16) unsigned recsL[ECAP];    // 4 KB
    __shared__ float2 ccL[32 * NREL];                 // 2 KB
    __shared__ int rsl[33];
    const int tid = threadIdx.x;
    const int wave = tid >> 6, lane = tid & 63;
    const int row0 = blockIdx.x * 32;

    // ---- phase 0a: stage rowStarts + per-node folded coeffs ----
    if (tid < 33) {
        int d = row0 + tid;
        rsl[tid] = (d < N) ? rowStart[d] : RE;
    }
    {
        int i = tid & 31, r = tid >> 5;     // 256 threads = 32 nodes x 8 rel
        int d = row0 + i;
        float2 cc = {0.f, 0.f};
        if (d < N) {
            int dv = deg[r * N + d];
            float inv = (dv > 0) ? 1.0f / (float)dv : 0.f;
            cc.x = coeff[2 * r] * inv;
            cc.y = coeff[2 * r + 1] * inv;
        }
        ccL[i * NREL + r] = cc;
    }
    __syncthreads();
    const int e0 = rsl[0];
    const int cntE = rsl[32] - e0;
    const bool fits = (cntE <= ECAP);
    {
        const int lim = fits ? cntE : 0;
        for (int k = tid; k < lim; k += 256)
            recsL[k] = recs[e0 + k];
    }
    __syncthreads();

    // ---- phase 1: gather (quarter-wave per node) ----
    {
        const int qw = tid >> 4;        // quarter-wave id 0..15
        const int h  = tid & 15;        // feature slot: feats 8h..8h+7

        auto gatherNode = [&](int i, auto getRec) {
            const int s   = rsl[i] - e0;
            const int len = rsl[i + 1] - rsl[i];
            f32x2 A0 = {0.f,0.f}, A1 = {0.f,0.f}, A2 = {0.f,0.f}, A3 = {0.f,0.f};
            f32x2 B0 = {0.f,0.f}, B1 = {0.f,0.f}, B2 = {0.f,0.f}, B3 = {0.f,0.f};
            if (len > 0) {
                const int last = s + len - 1;
                for (int k = 0; k < len; k += 8) {
                    unsigned rc[8];
                    #pragma unroll
                    for (int j = 0; j < 8; ++j) {
                        int li = s + k + j;
                        rc[j] = getRec(li <= last ? li : last);
                    }
                    uint4 u[8];
                    #pragma unroll
                    for (int j = 0; j < 8; ++j)
                        u[j] = *(const uint4*)(xb + (size_t)(rc[j] & 0x1FFFFu) * DFEAT + h * 8);
                    #pragma unroll
                    for (int j = 0; j < 8; ++j) {
                        bool v = (k + j) < len;
                        float2 cf = ccL[i * NREL + (rc[j] >> 17)];
                        float c0 = v ? cf.x : 0.f;
                        float c1 = v ? cf.y : 0.f;
                        f32x2 cc0 = {c0, c0}, cc1 = {c1, c1};
                        uint4 uu = u[j];
                        f32x2 f01 = {bflo(uu.x), bfhi(uu.x)};
                        f32x2 f23 = {bflo(uu.y), bfhi(uu.y)};
                        f32x2 f45 = {bflo(uu.z), bfhi(uu.z)};
                        f32x2 f67 = {bflo(uu.w), bfhi(uu.w)};
                        A0 += cc0 * f01; A1 += cc0 * f23; A2 += cc0 * f45; A3 += cc0 * f67;
                        B0 += cc1 * f01; B1 += cc1 * f23; B2 += cc1 * f45; B3 += cc1 * f67;
                    }
                }
            }
            uint4 w0, w1;
            w0.x = pack2bf(A0.x, A0.y); w0.y = pack2bf(A1.x, A1.y);
            w0.z = pack2bf(A2.x, A2.y); w0.w = pack2bf(A3.x, A3.y);
            w1.x = pack2bf(B0.x, B0.y); w1.y = pack2bf(B1.x, B1.y);
            w1.z = pack2bf(B2.x, B2.y); w1.w = pack2bf(B3.x, B3.y);
            *(uint4*)(agg + i * ALDA + h * 8)       = w0;   // c0 feats
            *(uint4*)(agg + i * ALDA + 128 + h * 8) = w1;   // c1 feats
        };

        if (fits) {
            #pragma unroll
            for (int p = 0; p < 2; ++p)
                gatherNode(qw + p * 16, [&](int li) { return recsL[li]; });
        } else {
            #pragma unroll
            for (int p = 0; p < 2; ++p)
                gatherNode(qw + p * 16, [&](int li) { return recs[e0 + li]; });
        }
    }
    __syncthreads();

    // ---- phase 2: GEMM (M=32) ----
    const int quad = lane >> 4, l16 = lane & 15;
    int arow[2];
    #pragma unroll
    for (int m = 0; m < 2; ++m) {
        int r = row0 + m * 16 + l16;
        arow[m] = (r < N) ? r : 0;
    }

    f32x4 zero = {0.f, 0.f, 0.f, 0.f};
    f32x4 acc[2][2] = {{zero, zero}, {zero, zero}};

    #pragma unroll
    for (int kt = 0; kt < 3; ++kt) {
        bf16x8 bq[4][2];
        #pragma unroll
        for (int t = 0; t < 4; ++t)
            #pragma unroll
            for (int g = 0; g < 2; ++g)
                bq[t][g] = *(const bf16x8*)(w2T + (size_t)(wave * 32 + g * 16 + l16) * 384
                                            + kt * 128 + t * 32 + quad * 8);
        #pragma unroll
        for (int m = 0; m < 2; ++m) {
            #pragma unroll
            for (int t = 0; t < 4; ++t) {
                bf16x8 a;
                if (kt < 2)
                    a = *(const bf16x8*)(agg + (m * 16 + l16) * ALDA + kt * 128 + t * 32 + quad * 8);
                else
                    a = *(const bf16x8*)(xb + (size_t)arow[m] * DFEAT + t * 32 + quad * 8);
                acc[m][0] = __builtin_amdgcn_mfma_f32_16x16x32_bf16(a, bq[t][0], acc[m][0], 0, 0, 0);
                acc[m][1] = __builtin_amdgcn_mfma_f32_16x16x32_bf16(a, bq[t][1], acc[m][1], 0, 0, 0);
            }
        }
    }

    #pragma unroll
    for (int g = 0; g < 2; ++g) {
        int c = wave * 32 + g * 16 + l16;
        float bv = bias[c];
        #pragma unroll
        for (int m = 0; m < 2; ++m) {
            #pragma unroll
            for (int reg = 0; reg < 4; ++reg) {
                int grow = row0 + m * 16 + quad * 4 + reg;
                if (grow < N)
                    out[(size_t)grow * DFEAT + c] = fmaxf(acc[m][g][reg] + bv, 0.f);
            }
        }
    }
}

extern "C" void kernel_launch(void* const* d_in, const int* in_sizes, int n_in,
                              void* d_out, int out_size, void* d_ws, size_t ws_size,
                              hipStream_t stream) {
    const float* x     = (const float*)d_in[0];
    const int*   src   = (const int*)  d_in[1];
    const int*   dst   = (const int*)  d_in[2];
    const float* coeff = (const float*)d_in[3];
    const float* bases = (const float*)d_in[4];
    const float* loopw = (const float*)d_in[5];
    const float* bias  = (const float*)d_in[6];
    float* out = (float*)d_out;

    const int N  = in_sizes[0] / DFEAT;            // 100000
    const int RE = in_sizes[1];                    // R*E = 1200000
    const int B  = in_sizes[4] / (DFEAT * DFEAT);  // 2
    const int R  = in_sizes[3] / B;                // 8
    const int E  = RE / R;                         // 150000
    const int NB = (N + 255) / 256;                // scan chunks (391)
    const int n4 = N * 32;

    // workspace layout
    char* ws = (char*)d_ws;
    size_t off = 0;
    auto alloc = [&](size_t bytes) { void* p = ws + off; off = (off + bytes + 255) & ~(size_t)255; return p; };
    int*      deg      = (int*)     alloc((size_t)R * N * sizeof(int));     // 3.2 MB
    ushort*   rank     = (ushort*)  alloc((size_t)RE * sizeof(ushort));     // 2.4 MB
    unsigned* packed   = (unsigned*)alloc((size_t)R * N * sizeof(unsigned));// 3.2 MB
    int*      rowStart = (int*)     alloc((size_t)N * sizeof(int));
    int*      bsums    = (int*)     alloc((size_t)NB * sizeof(int));
    ushort*   w2T      = (ushort*)  alloc((size_t)128 * 384 * sizeof(ushort));
    ushort*   xb       = (ushort*)  alloc((size_t)N * DFEAT * sizeof(ushort)); // 25.6 MB
    unsigned* recs     = (unsigned*)alloc((size_t)RE * sizeof(unsigned));      // 4.8 MB

    hipMemsetAsync(deg, 0, (size_t)R * N * sizeof(int), stream);
    fused_pre<<<4096, 256, 0, stream>>>(dst, deg, rank, x, xb, bases, loopw, w2T,
                                        RE, E, N, n4);
    scan_block_sums<<<NB, 256, 0, stream>>>(deg, bsums, N);
    scan_write<<<NB, 256, 0, stream>>>(bsums, deg, rowStart, packed, N);
    fill_kernel<<<(RE + 255) / 256, 256, 0, stream>>>(src, dst, rank, packed,
                                                      recs, RE, E, N);
    gather_gemm<<<(N + 31) / 32, 256, 0, stream>>>(recs, rowStart, deg, coeff,
                                                   xb, w2T, bias, out, N, RE);
}

// Round 11
// 279.659 us; speedup vs baseline: 1.0089x; 1.0089x over previous
//
#include <hip/hip_runtime.h>
#include <hip/hip_fp16.h>

// ---------------------------------------------------------------------------
// RelGraphConv (basis-decomposed, right-norm, sum over relations) on MI355X.
//
//   h[d] = B0^T * A0[d] + B1^T * A1[d] + x[d]@Wl + bias,  ReLU
//   A_b[d] = sum_{edges e->d} (coeff[r_e][b]/deg[r_e][d]) * x[src_e]
// R16: quarter-wave 16-edge predicated gather: 100us.
// R17/R18/R20: edge-centric stream / dual-node / lookback+cursor all
//   REGRESSED -> reverted.
// R19: LDS-staged recs + quarter-wave-owns-node gather.
// R21/R22: coop-fused pre abandoned (occupancy-capped coop grid; big coop
//   grids poison graph capture). Exposed recs scatter write-amplification.
// R23 (281.5us): R19 pipeline minus scan_mid.
// R24 (282.2us, =R23 within noise): 4-byte edge records (src|r<<17) +
//   per-block ccL[32][8] coeff/deg table; recs 9.6->4.8MB; LDS 25.2->23.2KB;
//   gather occ 45->53%, dur ~97us. Bank conflicts 800K->1.15M (ccL reads,
//   no visible cost). FETCH +10MB (ccL deg stage).
// R25: occupancy push on gather only: ECAP 1024->512 (cntE ~ Poisson(384),
//   P(>512)~0; global-recs fallback keeps correctness) -> LDS 21.2KB ->
//   7 blocks/CU; launch_bounds(256,7). DECISION RULE: if occ rises but dur
//   doesn't, gather is at its LLC-random-BW ceiling (~2.4TB/s) -> stop
//   touching it.
// ---------------------------------------------------------------------------

#define DFEAT 128
#define NREL 8
#define ALDA 264   // LDS agg row stride in ushorts (256 data + 8 pad)
#define ECAP 512   // staged-recs capacity (block edge count ~Poisson(384))

typedef __attribute__((ext_vector_type(8))) short bf16x8;
typedef __attribute__((ext_vector_type(4))) float f32x4;
typedef __attribute__((ext_vector_type(2))) float f32x2;

__device__ __forceinline__ ushort f2bf(float f) {
    unsigned u = __float_as_uint(f);
    u += 0x7FFF + ((u >> 16) & 1);          // round-to-nearest-even
    return (ushort)(u >> 16);
}
__device__ __forceinline__ float bflo(unsigned u) { return __uint_as_float(u << 16); }
__device__ __forceinline__ float bfhi(unsigned u) { return __uint_as_float(u & 0xFFFF0000u); }
__device__ __forceinline__ unsigned pack2bf(float lo, float hi) {
    return (unsigned)f2bf(lo) | ((unsigned)f2bf(hi) << 16);
}

// Fused: count_rank (atomic-latency-bound) + convert_x + build_w2T (BW-bound).
// deg must be pre-zeroed. w2T[j][k]: k<256 -> bases[k>>7][k&127][j],
// else loopw[k-256][j].
__global__ void fused_pre(const int* __restrict__ dst, int* __restrict__ deg,
                          ushort* __restrict__ rank,
                          const float* __restrict__ x, ushort* __restrict__ xb,
                          const float* __restrict__ bases, const float* __restrict__ loopw,
                          ushort* __restrict__ w2T,
                          int RE, int E, int N, int n4) {
    const int stride = gridDim.x * blockDim.x;
    const int t0 = blockIdx.x * blockDim.x + threadIdx.x;
    for (int i = t0; i < RE; i += stride) {
        int r = i / E;
        int d = dst[i];
        rank[i] = (ushort)atomicAdd(&deg[r * N + d], 1);
    }
    for (int i = t0; i < n4; i += stride) {
        float4 v = ((const float4*)x)[i];
        ushort4 o;
        o.x = f2bf(v.x); o.y = f2bf(v.y); o.z = f2bf(v.z); o.w = f2bf(v.w);
        ((ushort4*)xb)[i] = o;
    }
    for (int i = t0; i < 128 * 384; i += stride) {
        int j = i / 384, k = i % 384;
        float v = (k < 256) ? bases[(k >> 7) * DFEAT * DFEAT + (k & 127) * DFEAT + j]
                            : loopw[(k - 256) * DFEAT + j];
        w2T[i] = f2bf(v);
    }
}

// Per 256-node chunk: bsums[b] = sum over chunk of (sum_r deg[r][d]).
__global__ void scan_block_sums(const int* __restrict__ deg,
                                int* __restrict__ bsums, int N) {
    __shared__ int sdata[256];
    int b = blockIdx.x, t = threadIdx.x;
    int idx = b * 256 + t;
    int sum = 0;
    if (idx < N) {
        #pragma unroll
        for (int r = 0; r < NREL; ++r) sum += deg[r * N + idx];
    }
    sdata[t] = sum; __syncthreads();
    for (int s = 128; s > 0; s >>= 1) {
        if (t < s) sdata[t] += sdata[t + s];
        __syncthreads();
    }
    if (t == 0) bsums[b] = sdata[0];
}

// rowStart[d] + packed[r*N+d] = ((rowStart[d]+prefix_r)<<11)|deg_rd.
// Self-computes chunk base = sum bsums[0..b) (raw, L2-hot, <=391 ints).
__global__ void scan_write(const int* __restrict__ bsums,
                           const int* __restrict__ deg,
                           int* __restrict__ rowStart, unsigned* __restrict__ packed,
                           int N) {
    __shared__ int sdata[256];
    int b = blockIdx.x, t = threadIdx.x;

    // chunk base: sum of raw bsums[0..b)
    int part = 0;
    for (int k = t; k < b; k += 256) part += bsums[k];
    sdata[t] = part; __syncthreads();
    for (int s = 128; s > 0; s >>= 1) {
        if (t < s) sdata[t] += sdata[t + s];
        __syncthreads();
    }
    const int boff = sdata[0];
    __syncthreads();

    // per-node degree sum (kept in regs for packed below)
    int idx = b * 256 + t;
    int dvs[NREL];
    int c = 0;
    if (idx < N) {
        #pragma unroll
        for (int r = 0; r < NREL; ++r) { dvs[r] = deg[r * N + idx]; c += dvs[r]; }
    }
    // local exclusive scan
    sdata[t] = c; __syncthreads();
    for (int off = 1; off < 256; off <<= 1) {
        int x = 0;
        if (t >= off) x = sdata[t - off];
        __syncthreads();
        if (t >= off) sdata[t] += x;
        __syncthreads();
    }
    int excl = sdata[t] - c;
    if (idx < N) {
        int rs = boff + excl;
        rowStart[idx] = rs;
        int pre = 0;
        #pragma unroll
        for (int r = 0; r < NREL; ++r) {
            int dv = dvs[r];
            packed[r * N + idx] = ((unsigned)(rs + pre) << 11) | (unsigned)dv;
            pre += dv;
        }
    }
}

// Atomic-free placement: pos = (packed>>11) + rank. ONE random read per edge.
// 4-byte record = src | r<<17. No coeff/deg payload.
__global__ void fill_kernel(const int* __restrict__ src, const int* __restrict__ dst,
                            const ushort* __restrict__ rank,
                            const unsigned* __restrict__ packed,
                            unsigned* __restrict__ recs, int RE, int E, int N) {
    int idx = blockIdx.x * blockDim.x + threadIdx.x;
    if (idx >= RE) return;
    int r = idx / E;
    int d = dst[idx];
    unsigned p = packed[r * N + d];
    int pos = (int)(p >> 11) + (int)rank[idx];
    recs[pos] = (unsigned)src[idx] | ((unsigned)r << 17);
}

// ---------------------------------------------------------------------------
// FUSED gather + GEMM. Block = 32 dst nodes. LDS: agg 16.9KB + recsL 2KB +
// ccL 2KB + rsl = 21.2KB -> 7 blocks/CU.
// Phase 0: stage rowStart[row0..row0+32], ccL[i][r]=coeff[r][b]/deg[r][d]
//   (256 thr, coalesced deg reads), and recs[e0..e1) into LDS.
// Phase 1: quarter-wave owns a node; 8-edge rounds, rec+cc from LDS
//   (broadcast), xb uint4 gather. f32 accumulate -> bf16 agg.
// Phase 2: out[32,128] = relu([aggLDS|xb][32,384] @ w2T^T + bias).
// ---------------------------------------------------------------------------
__global__ __launch_bounds__(256, 7) void gather_gemm(
    const unsigned* __restrict__ recs, const int* __restrict__ rowStart,
    const int* __restrict__ deg, const float* __restrict__ coeff,
    const ushort* __restrict__ xb,
    const ushort* __restrict__ w2T, const float* __restrict__ bias,
    float* __restrict__ out, int N, int RE) {
    __shared__ __align__(16) ushort agg[32 * ALDA];   // 16.9 KB
    __shared__ __align__(16) unsigned recsL[ECAP];    // 2 KB
    __shared__ float2 ccL[32 * NREL];                 // 2 KB
    __shared__ int rsl[33];
    const int tid = threadIdx.x;
    const int wave = tid >> 6, lane = tid & 63;
    const int row0 = blockIdx.x * 32;

    // ---- phase 0a: stage rowStarts + per-node folded coeffs ----
    if (tid < 33) {
        int d = row0 + tid;
        rsl[tid] = (d < N) ? rowStart[d] : RE;
    }
    {
        int i = tid & 31, r = tid >> 5;     // 256 threads = 32 nodes x 8 rel
        int d = row0 + i;
        float2 cc = {0.f, 0.f};
        if (d < N) {
            int dv = deg[r * N + d];
            float inv = (dv > 0) ? 1.0f / (float)dv : 0.f;
            cc.x = coeff[2 * r] * inv;
            cc.y = coeff[2 * r + 1] * inv;
        }
        ccL[i * NREL + r] = cc;
    }
    __syncthreads();
    const int e0 = rsl[0];
    const int cntE = rsl[32] - e0;
    const bool fits = (cntE <= ECAP);
    {
        const int lim = fits ? cntE : 0;
        for (int k = tid; k < lim; k += 256)
            recsL[k] = recs[e0 + k];
    }
    __syncthreads();

    // ---- phase 1: gather (quarter-wave per node) ----
    {
        const int qw = tid >> 4;        // quarter-wave id 0..15
        const int h  = tid & 15;        // feature slot: feats 8h..8h+7

        auto gatherNode = [&](int i, auto getRec) {
            const int s   = rsl[i] - e0;
            const int len = rsl[i + 1] - rsl[i];
            f32x2 A0 = {0.f,0.f}, A1 = {0.f,0.f}, A2 = {0.f,0.f}, A3 = {0.f,0.f};
            f32x2 B0 = {0.f,0.f}, B1 = {0.f,0.f}, B2 = {0.f,0.f}, B3 = {0.f,0.f};
            if (len > 0) {
                const int last = s + len - 1;
                for (int k = 0; k < len; k += 8) {
                    unsigned rc[8];
                    #pragma unroll
                    for (int j = 0; j < 8; ++j) {
                        int li = s + k + j;
                        rc[j] = getRec(li <= last ? li : last);
                    }
                    uint4 u[8];
                    #pragma unroll
                    for (int j = 0; j < 8; ++j)
                        u[j] = *(const uint4*)(xb + (size_t)(rc[j] & 0x1FFFFu) * DFEAT + h * 8);
                    #pragma unroll
                    for (int j = 0; j < 8; ++j) {
                        bool v = (k + j) < len;
                        float2 cf = ccL[i * NREL + (rc[j] >> 17)];
                        float c0 = v ? cf.x : 0.f;
                        float c1 = v ? cf.y : 0.f;
                        f32x2 cc0 = {c0, c0}, cc1 = {c1, c1};
                        uint4 uu = u[j];
                        f32x2 f01 = {bflo(uu.x), bfhi(uu.x)};
                        f32x2 f23 = {bflo(uu.y), bfhi(uu.y)};
                        f32x2 f45 = {bflo(uu.z), bfhi(uu.z)};
                        f32x2 f67 = {bflo(uu.w), bfhi(uu.w)};
                        A0 += cc0 * f01; A1 += cc0 * f23; A2 += cc0 * f45; A3 += cc0 * f67;
                        B0 += cc1 * f01; B1 += cc1 * f23; B2 += cc1 * f45; B3 += cc1 * f67;
                    }
                }
            }
            uint4 w0, w1;
            w0.x = pack2bf(A0.x, A0.y); w0.y = pack2bf(A1.x, A1.y);
            w0.z = pack2bf(A2.x, A2.y); w0.w = pack2bf(A3.x, A3.y);
            w1.x = pack2bf(B0.x, B0.y); w1.y = pack2bf(B1.x, B1.y);
            w1.z = pack2bf(B2.x, B2.y); w1.w = pack2bf(B3.x, B3.y);
            *(uint4*)(agg + i * ALDA + h * 8)       = w0;   // c0 feats
            *(uint4*)(agg + i * ALDA + 128 + h * 8) = w1;   // c1 feats
        };

        if (fits) {
            #pragma unroll
            for (int p = 0; p < 2; ++p)
                gatherNode(qw + p * 16, [&](int li) { return recsL[li]; });
        } else {
            #pragma unroll
            for (int p = 0; p < 2; ++p)
                gatherNode(qw + p * 16, [&](int li) { return recs[e0 + li]; });
        }
    }
    __syncthreads();

    // ---- phase 2: GEMM (M=32) ----
    const int quad = lane >> 4, l16 = lane & 15;
    int arow[2];
    #pragma unroll
    for (int m = 0; m < 2; ++m) {
        int r = row0 + m * 16 + l16;
        arow[m] = (r < N) ? r : 0;
    }

    f32x4 zero = {0.f, 0.f, 0.f, 0.f};
    f32x4 acc[2][2] = {{zero, zero}, {zero, zero}};

    #pragma unroll
    for (int kt = 0; kt < 3; ++kt) {
        bf16x8 bq[4][2];
        #pragma unroll
        for (int t = 0; t < 4; ++t)
            #pragma unroll
            for (int g = 0; g < 2; ++g)
                bq[t][g] = *(const bf16x8*)(w2T + (size_t)(wave * 32 + g * 16 + l16) * 384
                                            + kt * 128 + t * 32 + quad * 8);
        #pragma unroll
        for (int m = 0; m < 2; ++m) {
            #pragma unroll
            for (int t = 0; t < 4; ++t) {
                bf16x8 a;
                if (kt < 2)
                    a = *(const bf16x8*)(agg + (m * 16 + l16) * ALDA + kt * 128 + t * 32 + quad * 8);
                else
                    a = *(const bf16x8*)(xb + (size_t)arow[m] * DFEAT + t * 32 + quad * 8);
                acc[m][0] = __builtin_amdgcn_mfma_f32_16x16x32_bf16(a, bq[t][0], acc[m][0], 0, 0, 0);
                acc[m][1] = __builtin_amdgcn_mfma_f32_16x16x32_bf16(a, bq[t][1], acc[m][1], 0, 0, 0);
            }
        }
    }

    #pragma unroll
    for (int g = 0; g < 2; ++g) {
        int c = wave * 32 + g * 16 + l16;
        float bv = bias[c];
        #pragma unroll
        for (int m = 0; m < 2; ++m) {
            #pragma unroll
            for (int reg = 0; reg < 4; ++reg) {
                int grow = row0 + m * 16 + quad * 4 + reg;
                if (grow < N)
                    out[(size_t)grow * DFEAT + c] = fmaxf(acc[m][g][reg] + bv, 0.f);
            }
        }
    }
}

extern "C" void kernel_launch(void* const* d_in, const int* in_sizes, int n_in,
                              void* d_out, int out_size, void* d_ws, size_t ws_size,
                              hipStream_t stream) {
    const float* x     = (const float*)d_in[0];
    const int*   src   = (const int*)  d_in[1];
    const int*   dst   = (const int*)  d_in[2];
    const float* coeff = (const float*)d_in[3];
    const float* bases = (const float*)d_in[4];
    const float* loopw = (const float*)d_in[5];
    const float* bias  = (const float*)d_in[6];
    float* out = (float*)d_out;

    const int N  = in_sizes[0] / DFEAT;            // 100000
    const int RE = in_sizes[1];                    // R*E = 1200000
    const int B  = in_sizes[4] / (DFEAT * DFEAT);  // 2
    const int R  = in_sizes[3] / B;                // 8
    const int E  = RE / R;                         // 150000
    const int NB = (N + 255) / 256;                // scan chunks (391)
    const int n4 = N * 32;

    // workspace layout
    char* ws = (char*)d_ws;
    size_t off = 0;
    auto alloc = [&](size_t bytes) { void* p = ws + off; off = (off + bytes + 255) & ~(size_t)255; return p; };
    int*      deg      = (int*)     alloc((size_t)R * N * sizeof(int));     // 3.2 MB
    ushort*   rank     = (ushort*)  alloc((size_t)RE * sizeof(ushort));     // 2.4 MB
    unsigned* packed   = (unsigned*)alloc((size_t)R * N * sizeof(unsigned));// 3.2 MB
    int*      rowStart = (int*)     alloc((size_t)N * sizeof(int));
    int*      bsums    = (int*)     alloc((size_t)NB * sizeof(int));
    ushort*   w2T      = (ushort*)  alloc((size_t)128 * 384 * sizeof(ushort));
    ushort*   xb       = (ushort*)  alloc((size_t)N * DFEAT * sizeof(ushort)); // 25.6 MB
    unsigned* recs     = (unsigned*)alloc((size_t)RE * sizeof(unsigned));      // 4.8 MB

    hipMemsetAsync(deg, 0, (size_t)R * N * sizeof(int), stream);
    fused_pre<<<4096, 256, 0, stream>>>(dst, deg, rank, x, xb, bases, loopw, w2T,
                                        RE, E, N, n4);
    scan_block_sums<<<NB, 256, 0, stream>>>(deg, bsums, N);
    scan_write<<<NB, 256, 0, stream>>>(bsums, deg, rowStart, packed, N);
    fill_kernel<<<(RE + 255) / 256, 256, 0, stream>>>(src, dst, rank, packed,
                                                      recs, RE, E, N);
    gather_gemm<<<(N + 31) / 32, 256, 0, stream>>>(recs, rowStart, deg, coeff,
                                                   xb, w2T, bias, out, N, RE);
}

// Round 12
// 273.227 us; speedup vs baseline: 1.0327x; 1.0235x over previous
//
#include <hip/hip_runtime.h>
#include <hip/hip_fp16.h>

// ---------------------------------------------------------------------------
// RelGraphConv (basis-decomposed, right-norm, sum over relations) on MI355X.
//
//   h[d] = B0^T * A0[d] + B1^T * A1[d] + x[d]@Wl + bias,  ReLU
//   A_b[d] = sum_{edges e->d} (coeff[r_e][b]/deg[r_e][d]) * x[src_e]
// R19-R25 history: gather evolved to LDS-staged recs + quarter-wave-owns-
//   node (R25: occ 62%, ~101us, flat vs 53% occ -> LLC-duty-cycle ceiling;
//   ROOFLINED, frozen). Pre-block stuck at ~178us vs ~45us stream roofline.
// R26: ATOMIC-STORM REMOVAL. Consistency check: R21's pre_all at 1/4 chip
//   took 317us; model [atomics ~130us occupancy-independent + streams
//   ~45us occupancy-scaled] predicts 310 (1/4) and 180 (full) -- both
//   match. So the 1.2M device-scope returning atomicAdds ARE the pre-block.
//   Replacement: two-level LDS counting sort, ZERO global returning atomics:
//   K1: per-block LDS hist over NBUCK=196 coarse buckets (d>>9), write
//       bh[bucket][block] + tot[bucket] (115K non-returning adds); also
//       does x->bf16 convert + w2T build (was fused_pre's stream work).
//   K2: 196 blocks: exclusive-scan bh column + self-computed bucket base
//       from L2-hot tot (no single-block scan kernel).
//   K3: re-read edges, LDS cursors from bh -> scatter recsC (4B rec =
//       src | r<<17 | dloc<<20) into bucket regions.
//   K4: one block per bucket: stream edges 2x: LDS cnt[512]+degL[512][8],
//       LDS scan -> rowStart/deg global, LDS-cursor scatter to final recs
//       (masked to src|r<<17; writes confined to the bucket's own window
//       -> no cross-XCD partial-line sharing). rank/packed/deg-memset GONE.
//   Edge order within a node becomes arbitrary: safe (R17/R24 evidence).
//   gather_gemm byte-identical to R25.
// ---------------------------------------------------------------------------

#define DFEAT 128
#define NREL 8
#define ALDA 264   // LDS agg row stride in ushorts (256 data + 8 pad)
#define ECAP 512   // staged-recs capacity in gather (block edges ~Poisson(384))
#define BSH 9      // 512 nodes per coarse bucket
#define EPB 1024   // edges per block in K1/K3

typedef __attribute__((ext_vector_type(8))) short bf16x8;
typedef __attribute__((ext_vector_type(4))) float f32x4;
typedef __attribute__((ext_vector_type(2))) float f32x2;

__device__ __forceinline__ ushort f2bf(float f) {
    unsigned u = __float_as_uint(f);
    u += 0x7FFF + ((u >> 16) & 1);          // round-to-nearest-even
    return (ushort)(u >> 16);
}
__device__ __forceinline__ float bflo(unsigned u) { return __uint_as_float(u << 16); }
__device__ __forceinline__ float bfhi(unsigned u) { return __uint_as_float(u & 0xFFFF0000u); }
__device__ __forceinline__ unsigned pack2bf(float lo, float hi) {
    return (unsigned)f2bf(lo) | ((unsigned)f2bf(hi) << 16);
}

// ---------------------------------------------------------------------------
// K1: coarse histogram (LDS) + x->xb convert + w2T build.
// bh layout: bh[bucket * B1 + block] (transposed for K2's coalesced scan).
// tot must be pre-zeroed (784B memset).
// ---------------------------------------------------------------------------
__global__ void k1_hist_conv(const int* __restrict__ dst,
                             const float* __restrict__ x, ushort* __restrict__ xb,
                             const float* __restrict__ bases, const float* __restrict__ loopw,
                             ushort* __restrict__ w2T,
                             int* __restrict__ bh, int* __restrict__ tot,
                             int RE, int N, int n4, int B1, int NBUCK) {
    __shared__ int hist[256];
    const int b = blockIdx.x, t = threadIdx.x;
    hist[t] = 0;
    __syncthreads();
    const int e0 = b * EPB;
    #pragma unroll
    for (int j = 0; j < EPB / 256; ++j) {
        int i = e0 + j * 256 + t;
        if (i < RE) atomicAdd(&hist[dst[i] >> BSH], 1);
    }
    __syncthreads();
    if (t < NBUCK) {
        int h = hist[t];
        bh[t * B1 + b] = h;
        if (h) atomicAdd(&tot[t], h);
    }
    // stream work: convert x -> bf16, build w2T
    const int stride = gridDim.x * blockDim.x;
    const int gt = b * 256 + t;
    for (int i = gt; i < n4; i += stride) {
        float4 v = ((const float4*)x)[i];
        ushort4 o;
        o.x = f2bf(v.x); o.y = f2bf(v.y); o.z = f2bf(v.z); o.w = f2bf(v.w);
        ((ushort4*)xb)[i] = o;
    }
    for (int i = gt; i < 128 * 384; i += stride) {
        int j = i / 384, k = i % 384;
        float v = (k < 256) ? bases[(k >> 7) * DFEAT * DFEAT + (k & 127) * DFEAT + j]
                            : loopw[(k - 256) * DFEAT + j];
        w2T[i] = f2bf(v);
    }
}

// ---------------------------------------------------------------------------
// K2: per-bucket exclusive scan of bh column (in place), base self-computed
// from tot[0..bu) (L2-hot, <=196 ints).
// ---------------------------------------------------------------------------
__global__ void k2_scan(int* __restrict__ bh, const int* __restrict__ tot,
                        int B1, int NBUCK) {
    __shared__ int s[256];
    __shared__ int carry;
    const int bu = blockIdx.x, t = threadIdx.x;
    // bucket base
    int part = 0;
    for (int k = t; k < bu; k += 256) part += tot[k];
    s[t] = part; __syncthreads();
    for (int off = 128; off > 0; off >>= 1) {
        if (t < off) s[t] += s[t + off];
        __syncthreads();
    }
    if (t == 0) carry = s[0];
    __syncthreads();
    // tiled exclusive scan over the column
    int* col = bh + (size_t)bu * B1;
    for (int base = 0; base < B1; base += 256) {
        int idx = base + t;
        int v = (idx < B1) ? col[idx] : 0;
        s[t] = v; __syncthreads();
        for (int off = 1; off < 256; off <<= 1) {
            int x = (t >= off) ? s[t - off] : 0;
            __syncthreads();
            s[t] += x;
            __syncthreads();
        }
        if (idx < B1) col[idx] = carry + s[t] - v;
        __syncthreads();
        if (t == 0) carry += s[255];
        __syncthreads();
    }
}

// ---------------------------------------------------------------------------
// K3: scatter edges into coarse-bucket regions. LDS cursors seeded from bh
// (same block<->edge-chunk mapping as K1). rec = src | r<<17 | dloc<<20.
// ---------------------------------------------------------------------------
__global__ void k3_scatter(const int* __restrict__ src, const int* __restrict__ dst,
                           const int* __restrict__ bh, unsigned* __restrict__ recsC,
                           int RE, int E, int B1, int NBUCK) {
    __shared__ int cursor[256];
    const int b = blockIdx.x, t = threadIdx.x;
    if (t < NBUCK) cursor[t] = bh[t * B1 + b];
    __syncthreads();
    const int e0 = b * EPB;
    #pragma unroll
    for (int j = 0; j < EPB / 256; ++j) {
        int i = e0 + j * 256 + t;
        if (i < RE) {
            int d = dst[i];
            int r = i / E;
            int slot = atomicAdd(&cursor[d >> BSH], 1);
            recsC[slot] = (unsigned)src[i] | ((unsigned)r << 17)
                        | ((unsigned)(d & 511) << 20);
        }
    }
}

// ---------------------------------------------------------------------------
// K4: one block per bucket. Stream edges twice (coalesced): count per node
// + per (node,rel) in LDS; LDS scan -> rowStart/deg; LDS-cursor scatter to
// final recs (masked to src|r<<17). Bucket base/end self-computed from tot.
// ---------------------------------------------------------------------------
__global__ void k4_bucket(const unsigned* __restrict__ recsC,
                          const int* __restrict__ tot,
                          int* __restrict__ rowStart, int* __restrict__ deg,
                          unsigned* __restrict__ recs, int N, int NBUCK) {
    __shared__ int cnt[512];
    __shared__ int degL[512 * NREL];    // 16 KB
    __shared__ int scanS[256];
    __shared__ int start[512];
    const int bu = blockIdx.x, t = threadIdx.x;

    // bucket base/end from tot
    int part = 0;
    for (int k = t; k < bu; k += 256) part += tot[k];
    scanS[t] = part; __syncthreads();
    for (int off = 128; off > 0; off >>= 1) {
        if (t < off) scanS[t] += scanS[t + off];
        __syncthreads();
    }
    const int base = scanS[0];
    __syncthreads();
    const int end = base + tot[bu];

    cnt[t] = 0; cnt[t + 256] = 0;
    for (int k = t; k < 512 * NREL; k += 256) degL[k] = 0;
    __syncthreads();

    // pass A: count
    for (int e = base + t; e < end; e += 256) {
        unsigned rc = recsC[e];
        int dloc = rc >> 20;
        int r = (rc >> 17) & 7;
        atomicAdd(&cnt[dloc], 1);
        atomicAdd(&degL[dloc * NREL + r], 1);
    }
    __syncthreads();

    // exclusive scan of cnt[512] with 256 threads (pair + scan + fixup)
    int c0 = cnt[2 * t], c1 = cnt[2 * t + 1];
    int ps = c0 + c1;
    scanS[t] = ps; __syncthreads();
    for (int off = 1; off < 256; off <<= 1) {
        int x = (t >= off) ? scanS[t - off] : 0;
        __syncthreads();
        scanS[t] += x;
        __syncthreads();
    }
    int excl = scanS[t] - ps;
    start[2 * t] = excl;
    start[2 * t + 1] = excl + c0;
    __syncthreads();

    // write rowStart + deg; init cursors (reuse cnt)
    const int d0 = bu << BSH;
    { int d = d0 + t;       if (d < N) rowStart[d] = base + start[t]; }
    { int d = d0 + 256 + t; if (d < N) rowStart[d] = base + start[256 + t]; }
    for (int k = t; k < 512 * NREL; k += 256) {
        int d = d0 + (k >> 3);
        int r = k & 7;
        if (d < N) deg[r * N + d] = degL[k];
    }
    __syncthreads();
    cnt[t] = start[t]; cnt[t + 256] = start[t + 256];
    __syncthreads();

    // pass B: scatter to final recs (bucket-local window)
    for (int e = base + t; e < end; e += 256) {
        unsigned rc = recsC[e];
        int dloc = rc >> 20;
        int slot = base + atomicAdd(&cnt[dloc], 1);
        recs[slot] = rc & 0xFFFFFu;     // src | r<<17
    }
}

// ---------------------------------------------------------------------------
// FUSED gather + GEMM (R25-exact; ROOFLINED, frozen). Block = 32 dst nodes.
// LDS: agg 16.9KB + recsL 2KB + ccL 2KB + rsl = 21.2KB -> 7 blocks/CU.
// ---------------------------------------------------------------------------
__global__ __launch_bounds__(256, 7) void gather_gemm(
    const unsigned* __restrict__ recs, const int* __restrict__ rowStart,
    const int* __restrict__ deg, const float* __restrict__ coeff,
    const ushort* __restrict__ xb,
    const ushort* __restrict__ w2T, const float* __restrict__ bias,
    float* __restrict__ out, int N, int RE) {
    __shared__ __align__(16) ushort agg[32 * ALDA];   // 16.9 KB
    __shared__ __align__(16) unsigned recsL[ECAP];    // 2 KB
    __shared__ float2 ccL[32 * NREL];                 // 2 KB
    __shared__ int rsl[33];
    const int tid = threadIdx.x;
    const int wave = tid >> 6, lane = tid & 63;
    const int row0 = blockIdx.x * 32;

    // ---- phase 0a: stage rowStarts + per-node folded coeffs ----
    if (tid < 33) {
        int d = row0 + tid;
        rsl[tid] = (d < N) ? rowStart[d] : RE;
    }
    {
        int i = tid & 31, r = tid >> 5;     // 256 threads = 32 nodes x 8 rel
        int d = row0 + i;
        float2 cc = {0.f, 0.f};
        if (d < N) {
            int dv = deg[r * N + d];
            float inv = (dv > 0) ? 1.0f / (float)dv : 0.f;
            cc.x = coeff[2 * r] * inv;
            cc.y = coeff[2 * r + 1] * inv;
        }
        ccL[i * NREL + r] = cc;
    }
    __syncthreads();
    const int e0 = rsl[0];
    const int cntE = rsl[32] - e0;
    const bool fits = (cntE <= ECAP);
    {
        const int lim = fits ? cntE : 0;
        for (int k = tid; k < lim; k += 256)
            recsL[k] = recs[e0 + k];
    }
    __syncthreads();

    // ---- phase 1: gather (quarter-wave per node) ----
    {
        const int qw = tid >> 4;        // quarter-wave id 0..15
        const int h  = tid & 15;        // feature slot: feats 8h..8h+7

        auto gatherNode = [&](int i, auto getRec) {
            const int s   = rsl[i] - e0;
            const int len = rsl[i + 1] - rsl[i];
            f32x2 A0 = {0.f,0.f}, A1 = {0.f,0.f}, A2 = {0.f,0.f}, A3 = {0.f,0.f};
            f32x2 B0 = {0.f,0.f}, B1 = {0.f,0.f}, B2 = {0.f,0.f}, B3 = {0.f,0.f};
            if (len > 0) {
                const int last = s + len - 1;
                for (int k = 0; k < len; k += 8) {
                    unsigned rc[8];
                    #pragma unroll
                    for (int j = 0; j < 8; ++j) {
                        int li = s + k + j;
                        rc[j] = getRec(li <= last ? li : last);
                    }
                    uint4 u[8];
                    #pragma unroll
                    for (int j = 0; j < 8; ++j)
                        u[j] = *(const uint4*)(xb + (size_t)(rc[j] & 0x1FFFFu) * DFEAT + h * 8);
                    #pragma unroll
                    for (int j = 0; j < 8; ++j) {
                        bool v = (k + j) < len;
                        float2 cf = ccL[i * NREL + (rc[j] >> 17)];
                        float c0 = v ? cf.x : 0.f;
                        float c1 = v ? cf.y : 0.f;
                        f32x2 cc0 = {c0, c0}, cc1 = {c1, c1};
                        uint4 uu = u[j];
                        f32x2 f01 = {bflo(uu.x), bfhi(uu.x)};
                        f32x2 f23 = {bflo(uu.y), bfhi(uu.y)};
                        f32x2 f45 = {bflo(uu.z), bfhi(uu.z)};
                        f32x2 f67 = {bflo(uu.w), bfhi(uu.w)};
                        A0 += cc0 * f01; A1 += cc0 * f23; A2 += cc0 * f45; A3 += cc0 * f67;
                        B0 += cc1 * f01; B1 += cc1 * f23; B2 += cc1 * f45; B3 += cc1 * f67;
                    }
                }
            }
            uint4 w0, w1;
            w0.x = pack2bf(A0.x, A0.y); w0.y = pack2bf(A1.x, A1.y);
            w0.z = pack2bf(A2.x, A2.y); w0.w = pack2bf(A3.x, A3.y);
            w1.x = pack2bf(B0.x, B0.y); w1.y = pack2bf(B1.x, B1.y);
            w1.z = pack2bf(B2.x, B2.y); w1.w = pack2bf(B3.x, B3.y);
            *(uint4*)(agg + i * ALDA + h * 8)       = w0;   // c0 feats
            *(uint4*)(agg + i * ALDA + 128 + h * 8) = w1;   // c1 feats
        };

        if (fits) {
            #pragma unroll
            for (int p = 0; p < 2; ++p)
                gatherNode(qw + p * 16, [&](int li) { return recsL[li]; });
        } else {
            #pragma unroll
            for (int p = 0; p < 2; ++p)
                gatherNode(qw + p * 16, [&](int li) { return recs[e0 + li]; });
        }
    }
    __syncthreads();

    // ---- phase 2: GEMM (M=32) ----
    const int quad = lane >> 4, l16 = lane & 15;
    int arow[2];
    #pragma unroll
    for (int m = 0; m < 2; ++m) {
        int r = row0 + m * 16 + l16;
        arow[m] = (r < N) ? r : 0;
    }

    f32x4 zero = {0.f, 0.f, 0.f, 0.f};
    f32x4 acc[2][2] = {{zero, zero}, {zero, zero}};

    #pragma unroll
    for (int kt = 0; kt < 3; ++kt) {
        bf16x8 bq[4][2];
        #pragma unroll
        for (int t = 0; t < 4; ++t)
            #pragma unroll
            for (int g = 0; g < 2; ++g)
                bq[t][g] = *(const bf16x8*)(w2T + (size_t)(wave * 32 + g * 16 + l16) * 384
                                            + kt * 128 + t * 32 + quad * 8);
        #pragma unroll
        for (int m = 0; m < 2; ++m) {
            #pragma unroll
            for (int t = 0; t < 4; ++t) {
                bf16x8 a;
                if (kt < 2)
                    a = *(const bf16x8*)(agg + (m * 16 + l16) * ALDA + kt * 128 + t * 32 + quad * 8);
                else
                    a = *(const bf16x8*)(xb + (size_t)arow[m] * DFEAT + t * 32 + quad * 8);
                acc[m][0] = __builtin_amdgcn_mfma_f32_16x16x32_bf16(a, bq[t][0], acc[m][0], 0, 0, 0);
                acc[m][1] = __builtin_amdgcn_mfma_f32_16x16x32_bf16(a, bq[t][1], acc[m][1], 0, 0, 0);
            }
        }
    }

    #pragma unroll
    for (int g = 0; g < 2; ++g) {
        int c = wave * 32 + g * 16 + l16;
        float bv = bias[c];
        #pragma unroll
        for (int m = 0; m < 2; ++m) {
            #pragma unroll
            for (int reg = 0; reg < 4; ++reg) {
                int grow = row0 + m * 16 + quad * 4 + reg;
                if (grow < N)
                    out[(size_t)grow * DFEAT + c] = fmaxf(acc[m][g][reg] + bv, 0.f);
            }
        }
    }
}

extern "C" void kernel_launch(void* const* d_in, const int* in_sizes, int n_in,
                              void* d_out, int out_size, void* d_ws, size_t ws_size,
                              hipStream_t stream) {
    const float* x     = (const float*)d_in[0];
    const int*   src   = (const int*)  d_in[1];
    const int*   dst   = (const int*)  d_in[2];
    const float* coeff = (const float*)d_in[3];
    const float* bases = (const float*)d_in[4];
    const float* loopw = (const float*)d_in[5];
    const float* bias  = (const float*)d_in[6];
    float* out = (float*)d_out;

    const int N  = in_sizes[0] / DFEAT;            // 100000
    const int RE = in_sizes[1];                    // R*E = 1200000
    const int B  = in_sizes[4] / (DFEAT * DFEAT);  // 2
    const int R  = in_sizes[3] / B;                // 8
    const int E  = RE / R;                         // 150000
    const int n4 = N * 32;
    const int NBUCK = (N + 511) >> BSH;            // 196 (<=256 for N<=128K)
    const int B1 = (RE + EPB - 1) / EPB;           // 1172

    // workspace layout
    char* ws = (char*)d_ws;
    size_t off = 0;
    auto alloc = [&](size_t bytes) { void* p = ws + off; off = (off + bytes + 255) & ~(size_t)255; return p; };
    int*      deg      = (int*)     alloc((size_t)R * N * sizeof(int));        // 3.2 MB
    int*      rowStart = (int*)     alloc((size_t)N * sizeof(int));            // 0.4 MB
    int*      tot      = (int*)     alloc((size_t)NBUCK * sizeof(int));        // 784 B
    int*      bh       = (int*)     alloc((size_t)NBUCK * B1 * sizeof(int));   // 0.92 MB
    ushort*   w2T      = (ushort*)  alloc((size_t)128 * 384 * sizeof(ushort)); // 96 KB
    ushort*   xb       = (ushort*)  alloc((size_t)N * DFEAT * sizeof(ushort)); // 25.6 MB
    unsigned* recsC    = (unsigned*)alloc((size_t)RE * sizeof(unsigned));      // 4.8 MB
    unsigned* recs     = (unsigned*)alloc((size_t)RE * sizeof(unsigned));      // 4.8 MB

    hipMemsetAsync(tot, 0, (size_t)NBUCK * sizeof(int), stream);
    k1_hist_conv<<<B1, 256, 0, stream>>>(dst, x, xb, bases, loopw, w2T,
                                         bh, tot, RE, N, n4, B1, NBUCK);
    k2_scan<<<NBUCK, 256, 0, stream>>>(bh, tot, B1, NBUCK);
    k3_scatter<<<B1, 256, 0, stream>>>(src, dst, bh, recsC, RE, E, B1, NBUCK);
    k4_bucket<<<NBUCK, 256, 0, stream>>>(recsC, tot, rowStart, deg, recs, N, NBUCK);
    gather_gemm<<<(N + 31) / 32, 256, 0, stream>>>(recs, rowStart, deg, coeff,
                                                   xb, w2T, bias, out, N, RE);
}